// Round 9
// baseline (259.473 us; speedup 1.0000x reference)
//
#include <hip/hip_runtime.h>
#include <hip/hip_fp16.h>

#define BN_EPS 1e-5f

typedef int      v4i __attribute__((ext_vector_type(4)));
typedef unsigned v4u __attribute__((ext_vector_type(4)));
typedef unsigned v2u __attribute__((ext_vector_type(2)));
typedef float    v4f __attribute__((ext_vector_type(4)));

__device__ __forceinline__ __half2 u2h2(unsigned u) {
    union { unsigned u; __half2 h; } c; c.u = u; return c.h;
}
__device__ __forceinline__ unsigned h22u(__half2 h) {
    union { unsigned u; __half2 h; } c; c.h = h; return c.u;
}

// ---------------------------------------------------------------------------
// K0: pack f32 [N][12] rows into fp16 [N][16] (32 B rows, line-aligned,
// zero-padded).
// ---------------------------------------------------------------------------
__global__ void k_pack_half(const float* __restrict__ emb,
                            __half2* __restrict__ hemb, int N) {
    int n = blockIdx.x * blockDim.x + threadIdx.x;
    if (n >= N) return;
    const float* r = emb + (size_t)n * 12;
    union { int4 v[2]; __half2 h[8]; } u;
    #pragma unroll
    for (int k = 0; k < 6; ++k) u.h[k] = __floats2half2_rn(r[2 * k], r[2 * k + 1]);
    u.h[6] = __floats2half2_rn(0.f, 0.f);
    u.h[7] = u.h[6];
    int4* dst = (int4*)(hemb + (size_t)n * 8);
    dst[0] = u.v[0];
    dst[1] = u.v[1];
}

// partial dot over 8 packed halves (4 uints) of each operand
__device__ __forceinline__ float dot8(int4 a, int4 b) {
    union U { int4 v; unsigned u[4]; };
    U x{a}, y{b};
    float s = 0.f;
    #pragma unroll
    for (int k = 0; k < 4; ++k) {
        float2 fa = __half22float2(u2h2(x.u[k]));
        float2 fb = __half22float2(u2h2(y.u[k]));
        s = fmaf(fa.x, fb.x, s);
        s = fmaf(fa.y, fb.y, s);
    }
    return s;
}

// ---------------------------------------------------------------------------
// K1 (fused, lane-pair): lanes 2p/2p+1 co-own 4 edges. Lane 2p loads bytes
// [0,16) of each row (dims 0-7), lane 2p+1 loads [16,32) (dims 8-11 + zero
// pad). The pair's two 16 B loads fall in the SAME 64 B line (rows are
// 32 B-aligned) -> the TA coalesces them to ONE line-request per row: the
// minimal 2 divergent requests/edge, with half the divergent instructions
// of the r5 fused kernel (no int2 second load). Partial dots are combined
// with shfl_xor(1); the even lane stores 4 packed fp16 (coalesced).
// ---------------------------------------------------------------------------
__global__ __launch_bounds__(256) void k_dot_fused2(
        const __half2* __restrict__ hs,
        const __half2* __restrict__ hd,
        const int* __restrict__ gsrc,
        const int* __restrict__ gdst,
        __half* __restrict__ like,
        double* __restrict__ acc,   // acc[0]=sum, acc[1]=sumsq
        int E) {
    int tid  = blockIdx.x * blockDim.x + threadIdx.x;
    int pair = tid >> 1;
    int half = tid & 1;            // which 16 B half of the 32 B row
    int e0   = pair * 4;
    float lsum = 0.f, lsq = 0.f;

    if (e0 + 4 <= E) {
        // both lanes of the pair load the same 4 edges' indices (broadcast-
        // coalesced: adjacent lanes hit the same 16 B)
        v4i s4 = __builtin_nontemporal_load((const v4i*)(gsrc + e0));
        v4i d4 = __builtin_nontemporal_load((const v4i*)(gdst + e0));
        int is[4] = {s4.x, s4.y, s4.z, s4.w};
        int id[4] = {d4.x, d4.y, d4.z, d4.w};

        // issue all 8 row-half loads before any use (MLP)
        int4 sr[4], dr[4];
        #pragma unroll
        for (int k = 0; k < 4; ++k) {
            sr[k] = ((const int4*)(hs + (size_t)is[k] * 8))[half];
            dr[k] = ((const int4*)(hd + (size_t)id[k] * 8))[half];
        }

        float dv[4];
        #pragma unroll
        for (int k = 0; k < 4; ++k) {
            float p = dot8(sr[k], dr[k]);
            p += __shfl_xor(p, 1);     // combine the two dimension halves
            dv[k] = p;
        }
        if (half == 0) {
            #pragma unroll
            for (int k = 0; k < 4; ++k) {
                lsum += dv[k];
                lsq  = fmaf(dv[k], dv[k], lsq);
            }
            v2u o;
            o.x = h22u(__floats2half2_rn(dv[0], dv[1]));
            o.y = h22u(__floats2half2_rn(dv[2], dv[3]));
            __builtin_nontemporal_store(o, (v2u*)(like + e0));
        }
    } else {
        for (int e = e0; e < E; ++e) {
            int4 a = ((const int4*)(hs + (size_t)gsrc[e] * 8))[half];
            int4 b = ((const int4*)(hd + (size_t)gdst[e] * 8))[half];
            float p = dot8(a, b);
            p += __shfl_xor(p, 1);
            if (half == 0) {
                like[e] = __float2half(p);
                lsum += p;
                lsq  += p * p;
            }
        }
    }

    for (int off = 32; off > 0; off >>= 1) {
        lsum += __shfl_down(lsum, off);
        lsq  += __shfl_down(lsq, off);
    }
    __shared__ float ssum[4], ssq[4];
    int wave = threadIdx.x >> 6;
    int lane = threadIdx.x & 63;
    if (lane == 0) { ssum[wave] = lsum; ssq[wave] = lsq; }
    __syncthreads();
    if (threadIdx.x == 0) {
        float ts = 0.f, tq = 0.f;
        for (int i = 0; i < 4; ++i) { ts += ssum[i]; tq += ssq[i]; }
        atomicAdd(&acc[0], (double)ts);
        atomicAdd(&acc[1], (double)tq);
    }
}

// ---------------------------------------------------------------------------
// K2: fold batch stats + bn affine into (scale, shift).
// ---------------------------------------------------------------------------
__global__ void k_params(const double* __restrict__ acc,
                         const float* __restrict__ bnw,
                         const float* __restrict__ bnb,
                         float* __restrict__ params,
                         int E) {
    double mean = acc[0] / (double)E;
    double var  = acc[1] / (double)E - mean * mean;
    float invstd = rsqrtf((float)var + BN_EPS);
    float scale = bnw[0] * invstd;
    params[0] = scale;
    params[1] = bnb[0] - (float)mean * scale;
}

// ---------------------------------------------------------------------------
// K3: LDS-privatized segment sum (64 KB static LDS -> 2 WG/CU), NT streams,
// slab output, no global atomics.
// ---------------------------------------------------------------------------
#define BUCKET 16000
__global__ __launch_bounds__(512) void k_bucket_scatter(
        const __half* __restrict__ like,
        const int* __restrict__ gsrc,
        const float* __restrict__ params,
        float* __restrict__ slab,   // [(p*G + g) * BUCKET]
        int E, int G) {
    __shared__ float sm[BUCKET];
    const int g  = blockIdx.x;
    const int p  = blockIdx.y;
    const int lo = p * BUCKET;

    for (int i = threadIdx.x; i < BUCKET; i += blockDim.x) sm[i] = 0.f;
    __syncthreads();

    const float scale = params[0];
    const float shift = params[1];

    int per = (E + G - 1) / G;
    per = (per + 3) & ~3;
    const int s0 = g * per;
    const int s1 = min(s0 + per, E);

    for (int e = s0 + (int)threadIdx.x * 4; e < s1; e += (int)blockDim.x * 4) {
        if (e + 4 <= s1) {
            v4i n4 = __builtin_nontemporal_load((const v4i*)(gsrc + e));
            v2u l2 = __builtin_nontemporal_load((const v2u*)(like + e));
            float2 fa = __half22float2(u2h2(l2.x));
            float2 fb = __half22float2(u2h2(l2.y));
            unsigned o0 = (unsigned)(n4.x - lo);
            unsigned o1 = (unsigned)(n4.y - lo);
            unsigned o2 = (unsigned)(n4.z - lo);
            unsigned o3 = (unsigned)(n4.w - lo);
            if (o0 < BUCKET) atomicAdd(&sm[o0], __expf(fmaf(fa.x, scale, shift)));
            if (o1 < BUCKET) atomicAdd(&sm[o1], __expf(fmaf(fa.y, scale, shift)));
            if (o2 < BUCKET) atomicAdd(&sm[o2], __expf(fmaf(fb.x, scale, shift)));
            if (o3 < BUCKET) atomicAdd(&sm[o3], __expf(fmaf(fb.y, scale, shift)));
        } else {
            for (int k = 0; e + k < s1; ++k) {
                unsigned o = (unsigned)(gsrc[e + k] - lo);
                if (o < BUCKET)
                    atomicAdd(&sm[o], __expf(fmaf(__half2float(like[e + k]), scale, shift)));
            }
        }
    }
    __syncthreads();

    float* dst = slab + ((size_t)p * G + g) * BUCKET;
    for (int i = threadIdx.x; i < BUCKET; i += blockDim.x)
        __builtin_nontemporal_store(sm[i], dst + i);
}

// ---------------------------------------------------------------------------
// K3b: fold slabs: denom[n] = sum_g slab[(p(n)*G + g)*BUCKET + n%BUCKET]
// ---------------------------------------------------------------------------
__global__ void k_fold(const float* __restrict__ slab,
                       float* __restrict__ denom, int N, int G) {
    int n = blockIdx.x * blockDim.x + threadIdx.x;
    if (n >= N) return;
    int p   = n / BUCKET;
    int off = n - p * BUCKET;
    const float* s = slab + (size_t)p * G * BUCKET + off;
    float acc = 0.f;
    for (int g = 0; g < G; ++g)
        acc += __builtin_nontemporal_load(s + (size_t)g * BUCKET);
    denom[n] = acc;
}

// ---------------------------------------------------------------------------
// K4: out[e] = exp(like*scale+shift) / (1e-12 + denom[gsrc[e]])
// ---------------------------------------------------------------------------
__global__ void k_normalize(const __half* __restrict__ like,
                            const int* __restrict__ gsrc,
                            const float* __restrict__ params,
                            const float* __restrict__ denom,
                            float* __restrict__ out,
                            int E) {
    const float scale = params[0];
    const float shift = params[1];
    int e = (blockIdx.x * blockDim.x + threadIdx.x) * 4;
    if (e + 4 <= E) {
        v4i n4 = __builtin_nontemporal_load((const v4i*)(gsrc + e));
        v2u l2 = __builtin_nontemporal_load((const v2u*)(like + e));
        float2 fa = __half22float2(u2h2(l2.x));
        float2 fb = __half22float2(u2h2(l2.y));
        v4f o;
        o.x = __expf(fmaf(fa.x, scale, shift)) / (1e-12f + denom[n4.x]);
        o.y = __expf(fmaf(fa.y, scale, shift)) / (1e-12f + denom[n4.y]);
        o.z = __expf(fmaf(fb.x, scale, shift)) / (1e-12f + denom[n4.z]);
        o.w = __expf(fmaf(fb.y, scale, shift)) / (1e-12f + denom[n4.w]);
        __builtin_nontemporal_store(o, (v4f*)(out + e));
    } else {
        for (; e < E; ++e)
            out[e] = __expf(fmaf(__half2float(like[e]), scale, shift)) /
                     (1e-12f + denom[gsrc[e]]);
    }
}

// Fallback (agent-scope atomics) if ws can't hold the slab.
__global__ void k_exp_scatter_agent(const __half* __restrict__ like,
                                    const int* __restrict__ gsrc,
                                    const float* __restrict__ params,
                                    float* __restrict__ denom,
                                    int E) {
    float scale = params[0];
    float shift = params[1];
    for (int e = blockIdx.x * blockDim.x + threadIdx.x; e < E;
         e += gridDim.x * blockDim.x) {
        atomicAdd(&denom[gsrc[e]],
                  __expf(fmaf(__half2float(like[e]), scale, shift)));
    }
}

extern "C" void kernel_launch(void* const* d_in, const int* in_sizes, int n_in,
                              void* d_out, int out_size, void* d_ws, size_t ws_size,
                              hipStream_t stream) {
    const float* src_emb = (const float*)d_in[0];
    const float* dst_emb = (const float*)d_in[1];
    const float* bnw     = (const float*)d_in[2];
    const float* bnb     = (const float*)d_in[3];
    const int*   gsrc    = (const int*)d_in[4];
    const int*   gdst    = (const int*)d_in[5];

    const int E = in_sizes[4];           // 3,200,000 edges
    const int N = in_sizes[0] / 12;      // 100,000 nodes
    float* out = (float*)d_out;

    const int P = (N + BUCKET - 1) / BUCKET;   // node buckets (7)

    // workspace layout (64B-aligned regions):
    //   acc(16)|params(16)|pad | like(2E) | denom(4N) | hs(32N) | hd(32N) |
    //   slab (P*G*BUCKET*4)
    char* ws = (char*)d_ws;
    double*  acc    = (double*)ws;
    float*   params = (float*)(ws + 16);
    size_t   off    = 64;
    __half*  like   = (__half*)(ws + off);  off += ((size_t)E * 2 + 63) & ~(size_t)63;
    float*   denom  = (float*)(ws + off);   off += ((size_t)N * 4 + 63) & ~(size_t)63;
    __half2* hs     = (__half2*)(ws + off); off += ((size_t)N * 32 + 63) & ~(size_t)63;
    __half2* hd     = (__half2*)(ws + off); off += ((size_t)N * 32 + 63) & ~(size_t)63;
    float*   slab   = (float*)(ws + off);

    size_t rem = (ws_size > off) ? ws_size - off : 0;
    int G = 0;
    for (int cand = 64; cand >= 8; cand >>= 1) {
        if ((size_t)P * cand * BUCKET * 4 <= rem) { G = cand; break; }
    }

    const int block = 256;

    hipMemsetAsync(ws, 0, 32, stream);

    k_pack_half<<<(N + block - 1) / block, block, 0, stream>>>(src_emb, hs, N);
    k_pack_half<<<(N + block - 1) / block, block, 0, stream>>>(dst_emb, hd, N);

    // 2 lanes per 4 edges -> threads = 2 * ceil(E/4)
    long long threads = 2LL * ((E + 3) / 4);
    int dot_blocks = (int)((threads + block - 1) / block);
    k_dot_fused2<<<dot_blocks, block, 0, stream>>>(hs, hd, gsrc, gdst,
                                                   like, acc, E);
    k_params<<<1, 1, 0, stream>>>(acc, bnw, bnb, params, E);

    if (G > 0) {
        dim3 grid(G, P);
        k_bucket_scatter<<<grid, 512, 0, stream>>>(like, gsrc, params, slab,
                                                   E, G);
        k_fold<<<(N + block - 1) / block, block, 0, stream>>>(slab, denom, N, G);
    } else {
        hipMemsetAsync(denom, 0, (size_t)N * 4, stream);
        int blocks = min((E + block - 1) / block, 4096);
        k_exp_scatter_agent<<<blocks, block, 0, stream>>>(like, gsrc, params,
                                                          denom, E);
    }

    k_normalize<<<(E / 4 + block - 1) / block, block, 0, stream>>>(
        like, gsrc, params, denom, out, E);
}

// Round 10
// 186.960 us; speedup vs baseline: 1.3879x; 1.3879x over previous
//
#include <hip/hip_runtime.h>
#include <hip/hip_fp16.h>

#define BN_EPS 1e-5f
#define BUCKET 20000        // nodes/bucket * 4B = 80,000 B dynamic LDS -> 2 WG/CU

typedef int      v4i __attribute__((ext_vector_type(4)));
typedef unsigned v4u __attribute__((ext_vector_type(4)));
typedef unsigned v2u __attribute__((ext_vector_type(2)));
typedef float    v4f __attribute__((ext_vector_type(4)));

__device__ __forceinline__ __half2 u2h2(unsigned u) {
    union { unsigned u; __half2 h; } c; c.u = u; return c.h;
}
__device__ __forceinline__ unsigned h22u(__half2 h) {
    union { unsigned u; __half2 h; } c; c.h = h; return c.u;
}

// scale/shift from raw stats (computed per block by thread 0)
__device__ __forceinline__ float2 bn_params(const double* acc,
                                            const float* bnw,
                                            const float* bnb, int E) {
    double mean = acc[0] / (double)E;
    double var  = acc[1] / (double)E - mean * mean;
    float scale = bnw[0] * rsqrtf((float)var + BN_EPS);
    float shift = bnb[0] - (float)mean * scale;
    return make_float2(scale, shift);
}

// ---------------------------------------------------------------------------
// K0: pack BOTH f32 [N][12] tables into fp16 [N][16] (32 B aligned rows),
// one launch (grid covers 2N rows).
// ---------------------------------------------------------------------------
__global__ void k_pack_both(const float* __restrict__ src_emb,
                            const float* __restrict__ dst_emb,
                            __half2* __restrict__ hs,
                            __half2* __restrict__ hd, int N) {
    int t = blockIdx.x * blockDim.x + threadIdx.x;
    int n = (t < N) ? t : t - N;
    if (t >= 2 * N) return;
    const float* r = ((t < N) ? src_emb : dst_emb) + (size_t)n * 12;
    __half2* hemb = (t < N) ? hs : hd;
    union { int4 v[2]; __half2 h[8]; } u;
    #pragma unroll
    for (int k = 0; k < 6; ++k) u.h[k] = __floats2half2_rn(r[2 * k], r[2 * k + 1]);
    u.h[6] = __floats2half2_rn(0.f, 0.f);
    u.h[7] = u.h[6];
    int4* dst = (int4*)(hemb + (size_t)n * 8);
    dst[0] = u.v[0];
    dst[1] = u.v[1];
}

// dot of two 12-half rows given as 6 packed uints each
__device__ __forceinline__ float rowdot12u(const unsigned* a, const unsigned* b) {
    float dot = 0.f;
    #pragma unroll
    for (int k = 0; k < 6; ++k) {
        float2 fa = __half22float2(u2h2(a[k]));
        float2 fb = __half22float2(u2h2(b[k]));
        dot = fmaf(fa.x, fb.x, dot);
        dot = fmaf(fa.y, fb.y, dot);
    }
    return dot;
}

__device__ __forceinline__ float rowdot(const int4* __restrict__ a,
                                        const int4* __restrict__ b) {
    union U { int4 v; unsigned u[4]; };
    U a0{a[0]}, a1{a[1]}, b0{b[0]}, b1{b[1]};
    unsigned au[6] = {a0.u[0], a0.u[1], a0.u[2], a0.u[3], a1.u[0], a1.u[1]};
    unsigned bu[6] = {b0.u[0], b0.u[1], b0.u[2], b0.u[3], b1.u[0], b1.u[1]};
    return rowdot12u(au, bu);
}

// ---------------------------------------------------------------------------
// K1: fused dot (r6-proven form, 8 edges/thread): NT index loads, normal
// gathers (tables want caching), fp16 like store, block-reduced stats.
// Bound by L2-miss fabric BW (~2.9 TB/s) -- structural for this footprint.
// ---------------------------------------------------------------------------
__global__ __launch_bounds__(256) void k_dot_fused(
        const __half2* __restrict__ hs,
        const __half2* __restrict__ hd,
        const int* __restrict__ gsrc,
        const int* __restrict__ gdst,
        __half* __restrict__ like,
        double* __restrict__ acc,   // acc[0]=sum, acc[1]=sumsq
        int E) {
    int e0 = (blockIdx.x * blockDim.x + threadIdx.x) * 8;
    float lsum = 0.f, lsq = 0.f;
    if (e0 + 8 <= E) {
        v4i s0 = __builtin_nontemporal_load((const v4i*)(gsrc + e0));
        v4i s1 = __builtin_nontemporal_load((const v4i*)(gsrc + e0 + 4));
        v4i d0 = __builtin_nontemporal_load((const v4i*)(gdst + e0));
        v4i d1 = __builtin_nontemporal_load((const v4i*)(gdst + e0 + 4));
        int is[8] = {s0.x, s0.y, s0.z, s0.w, s1.x, s1.y, s1.z, s1.w};
        int id[8] = {d0.x, d0.y, d0.z, d0.w, d1.x, d1.y, d1.z, d1.w};
        float dv[8];
        #pragma unroll
        for (int k = 0; k < 8; ++k) {
            dv[k] = rowdot((const int4*)(hs + (size_t)is[k] * 8),
                           (const int4*)(hd + (size_t)id[k] * 8));
            lsum += dv[k];
            lsq  = fmaf(dv[k], dv[k], lsq);
        }
        v4u o;
        o.x = h22u(__floats2half2_rn(dv[0], dv[1]));
        o.y = h22u(__floats2half2_rn(dv[2], dv[3]));
        o.z = h22u(__floats2half2_rn(dv[4], dv[5]));
        o.w = h22u(__floats2half2_rn(dv[6], dv[7]));
        __builtin_nontemporal_store(o, (v4u*)(like + e0));
    } else {
        for (int e = e0; e < E; ++e) {
            float d = rowdot((const int4*)(hs + (size_t)gsrc[e] * 8),
                             (const int4*)(hd + (size_t)gdst[e] * 8));
            like[e] = __float2half(d);
            lsum += d;
            lsq  += d * d;
        }
    }
    for (int off = 32; off > 0; off >>= 1) {
        lsum += __shfl_down(lsum, off);
        lsq  += __shfl_down(lsq, off);
    }
    __shared__ float ssum[4], ssq[4];
    int wave = threadIdx.x >> 6;
    int lane = threadIdx.x & 63;
    if (lane == 0) { ssum[wave] = lsum; ssq[wave] = lsq; }
    __syncthreads();
    if (threadIdx.x == 0) {
        float ts = 0.f, tq = 0.f;
        for (int i = 0; i < 4; ++i) { ts += ssum[i]; tq += ssq[i]; }
        atomicAdd(&acc[0], (double)ts);
        atomicAdd(&acc[1], (double)tq);
    }
}

// ---------------------------------------------------------------------------
// K3: LDS-privatized segment sum. 80 KB dynamic LDS (2 WG/CU), P=5 passes,
// G slices; computes (scale,shift) from raw stats in-kernel (no k_params
// launch); NT streams; slab output (no global atomics).
// ---------------------------------------------------------------------------
__global__ __launch_bounds__(512) void k_bucket_scatter(
        const __half* __restrict__ like,
        const int* __restrict__ gsrc,
        const double* __restrict__ acc,
        const float* __restrict__ bnw,
        const float* __restrict__ bnb,
        float* __restrict__ slab,   // [(p*G + g) * BUCKET]
        int E, int G) {
    extern __shared__ float sm[];
    __shared__ float2 s_par;
    const int g  = blockIdx.x;
    const int p  = blockIdx.y;
    const int lo = p * BUCKET;

    if (threadIdx.x == 0) s_par = bn_params(acc, bnw, bnb, E);
    for (int i = threadIdx.x; i < BUCKET; i += blockDim.x) sm[i] = 0.f;
    __syncthreads();

    const float scale = s_par.x;
    const float shift = s_par.y;

    int per = (E + G - 1) / G;
    per = (per + 3) & ~3;
    const int s0 = g * per;
    const int s1 = min(s0 + per, E);

    for (int e = s0 + (int)threadIdx.x * 4; e < s1; e += (int)blockDim.x * 4) {
        if (e + 4 <= s1) {
            v4i n4 = __builtin_nontemporal_load((const v4i*)(gsrc + e));
            v2u l2 = __builtin_nontemporal_load((const v2u*)(like + e));
            float2 fa = __half22float2(u2h2(l2.x));
            float2 fb = __half22float2(u2h2(l2.y));
            unsigned o0 = (unsigned)(n4.x - lo);
            unsigned o1 = (unsigned)(n4.y - lo);
            unsigned o2 = (unsigned)(n4.z - lo);
            unsigned o3 = (unsigned)(n4.w - lo);
            if (o0 < BUCKET) atomicAdd(&sm[o0], __expf(fmaf(fa.x, scale, shift)));
            if (o1 < BUCKET) atomicAdd(&sm[o1], __expf(fmaf(fa.y, scale, shift)));
            if (o2 < BUCKET) atomicAdd(&sm[o2], __expf(fmaf(fb.x, scale, shift)));
            if (o3 < BUCKET) atomicAdd(&sm[o3], __expf(fmaf(fb.y, scale, shift)));
        } else {
            for (int k = 0; e + k < s1; ++k) {
                unsigned o = (unsigned)(gsrc[e + k] - lo);
                if (o < BUCKET)
                    atomicAdd(&sm[o], __expf(fmaf(__half2float(like[e + k]), scale, shift)));
            }
        }
    }
    __syncthreads();

    float* dst = slab + ((size_t)p * G + g) * BUCKET;
    for (int i = threadIdx.x; i < BUCKET; i += blockDim.x)
        __builtin_nontemporal_store(sm[i], dst + i);
}

// ---------------------------------------------------------------------------
// K3b: fold slabs: denom[n] = sum_g slab[(p(n)*G + g)*BUCKET + n%BUCKET]
// ---------------------------------------------------------------------------
__global__ void k_fold(const float* __restrict__ slab,
                       float* __restrict__ denom, int N, int G) {
    int n = blockIdx.x * blockDim.x + threadIdx.x;
    if (n >= N) return;
    int p   = n / BUCKET;
    int off = n - p * BUCKET;
    const float* s = slab + (size_t)p * G * BUCKET + off;
    float acc = 0.f;
    for (int g = 0; g < G; ++g)
        acc += __builtin_nontemporal_load(s + (size_t)g * BUCKET);
    denom[n] = acc;
}

// ---------------------------------------------------------------------------
// K4: out[e] = exp(like*scale+shift) / (1e-12 + denom[gsrc[e]])
// (scale,shift) recomputed per block from raw stats.
// ---------------------------------------------------------------------------
__global__ void k_normalize(const __half* __restrict__ like,
                            const int* __restrict__ gsrc,
                            const double* __restrict__ acc,
                            const float* __restrict__ bnw,
                            const float* __restrict__ bnb,
                            const float* __restrict__ denom,
                            float* __restrict__ out,
                            int E) {
    __shared__ float2 s_par;
    if (threadIdx.x == 0) s_par = bn_params(acc, bnw, bnb, E);
    __syncthreads();
    const float scale = s_par.x;
    const float shift = s_par.y;
    int e = (blockIdx.x * blockDim.x + threadIdx.x) * 4;
    if (e + 4 <= E) {
        v4i n4 = __builtin_nontemporal_load((const v4i*)(gsrc + e));
        v2u l2 = __builtin_nontemporal_load((const v2u*)(like + e));
        float2 fa = __half22float2(u2h2(l2.x));
        float2 fb = __half22float2(u2h2(l2.y));
        v4f o;
        o.x = __expf(fmaf(fa.x, scale, shift)) / (1e-12f + denom[n4.x]);
        o.y = __expf(fmaf(fa.y, scale, shift)) / (1e-12f + denom[n4.y]);
        o.z = __expf(fmaf(fb.x, scale, shift)) / (1e-12f + denom[n4.z]);
        o.w = __expf(fmaf(fb.y, scale, shift)) / (1e-12f + denom[n4.w]);
        __builtin_nontemporal_store(o, (v4f*)(out + e));
    } else {
        for (; e < E; ++e)
            out[e] = __expf(fmaf(__half2float(like[e]), scale, shift)) /
                     (1e-12f + denom[gsrc[e]]);
    }
}

// Fallback (agent-scope atomics) if ws can't hold the slab.
__global__ void k_exp_scatter_agent(const __half* __restrict__ like,
                                    const int* __restrict__ gsrc,
                                    const double* __restrict__ acc,
                                    const float* __restrict__ bnw,
                                    const float* __restrict__ bnb,
                                    float* __restrict__ denom,
                                    int E) {
    __shared__ float2 s_par;
    if (threadIdx.x == 0) s_par = bn_params(acc, bnw, bnb, E);
    __syncthreads();
    const float scale = s_par.x;
    const float shift = s_par.y;
    for (int e = blockIdx.x * blockDim.x + threadIdx.x; e < E;
         e += gridDim.x * blockDim.x) {
        atomicAdd(&denom[gsrc[e]],
                  __expf(fmaf(__half2float(like[e]), scale, shift)));
    }
}

extern "C" void kernel_launch(void* const* d_in, const int* in_sizes, int n_in,
                              void* d_out, int out_size, void* d_ws, size_t ws_size,
                              hipStream_t stream) {
    const float* src_emb = (const float*)d_in[0];
    const float* dst_emb = (const float*)d_in[1];
    const float* bnw     = (const float*)d_in[2];
    const float* bnb     = (const float*)d_in[3];
    const int*   gsrc    = (const int*)d_in[4];
    const int*   gdst    = (const int*)d_in[5];

    const int E = in_sizes[4];           // 3,200,000 edges
    const int N = in_sizes[0] / 12;      // 100,000 nodes
    float* out = (float*)d_out;

    const int P = (N + BUCKET - 1) / BUCKET;   // 5 buckets

    // workspace layout (64B-aligned regions):
    //   acc(16)|pad | like(2E) | denom(4N) | hs(32N) | hd(32N) | slab
    char* ws = (char*)d_ws;
    double*  acc    = (double*)ws;
    size_t   off    = 64;
    __half*  like   = (__half*)(ws + off);  off += ((size_t)E * 2 + 63) & ~(size_t)63;
    float*   denom  = (float*)(ws + off);   off += ((size_t)N * 4 + 63) & ~(size_t)63;
    __half2* hs     = (__half2*)(ws + off); off += ((size_t)N * 32 + 63) & ~(size_t)63;
    __half2* hd     = (__half2*)(ws + off); off += ((size_t)N * 32 + 63) & ~(size_t)63;
    float*   slab   = (float*)(ws + off);

    size_t rem = (ws_size > off) ? ws_size - off : 0;
    int G = 0;
    for (int cand = 64; cand >= 8; cand >>= 1) {
        if ((size_t)P * cand * BUCKET * 4 <= rem) { G = cand; break; }
    }

    const int block = 256;

    hipMemsetAsync(ws, 0, 32, stream);

    k_pack_both<<<(2 * N + block - 1) / block, block, 0, stream>>>(
        src_emb, dst_emb, hs, hd, N);

    int dot_blocks = (E / 8 + block - 1) / block + 1;
    k_dot_fused<<<dot_blocks, block, 0, stream>>>(hs, hd, gsrc, gdst,
                                                  like, acc, E);

    if (G > 0) {
        dim3 grid(G, P);
        k_bucket_scatter<<<grid, 512, (size_t)BUCKET * 4, stream>>>(
            like, gsrc, acc, bnw, bnb, slab, E, G);
        k_fold<<<(N + block - 1) / block, block, 0, stream>>>(slab, denom, N, G);
    } else {
        hipMemsetAsync(denom, 0, (size_t)N * 4, stream);
        int blocks = min((E + block - 1) / block, 4096);
        k_exp_scatter_agent<<<blocks, block, 0, stream>>>(like, gsrc, acc,
                                                          bnw, bnb, denom, E);
    }

    k_normalize<<<(E / 4 + block - 1) / block, block, 0, stream>>>(
        like, gsrc, acc, bnw, bnb, denom, out, E);
}